// Round 1
// baseline (259.702 us; speedup 1.0000x reference)
//
#include <hip/hip_runtime.h>
#include <hip/hip_bf16.h>

#define T_LEN 28
#define EMB   28
#define HID   256
#define NOUT  10
#define BATCH 32768

typedef _Float16 f16x8 __attribute__((ext_vector_type(8)));
typedef _Float16 f16x4 __attribute__((ext_vector_type(4)));
typedef float    f32x4 __attribute__((ext_vector_type(4)));

// Re-layout W1/W2 into fp16 MFMA A-operand fragments.
// W2A: [jt(16)][kb(8)][lane(64)][i(8)]  -> A[j][k], j = jt*16+(l&15), k = kb*32+(l>>4)*8+i
// W1A: [jt(16)][lane(64)][i(8)]         -> A[j][e], e = (l>>4)*8+i (zero-padded e>=28)
__global__ void prep_kernel(const float* __restrict__ W1, const float* __restrict__ W2,
                            _Float16* __restrict__ W2A, _Float16* __restrict__ W1A) {
    int idx = blockIdx.x * 256 + threadIdx.x;
    if (idx < 65536) {
        int i  = idx & 7;
        int l  = (idx >> 3) & 63;
        int kb = (idx >> 9) & 7;
        int jt = idx >> 12;
        int j  = jt * 16 + (l & 15);
        int k  = kb * 32 + (l >> 4) * 8 + i;
        W2A[idx] = (_Float16)W2[j * HID + k];
    }
    if (idx < 8192) {
        int i  = idx & 7;
        int l  = (idx >> 3) & 63;
        int jt = idx >> 9;
        int j  = jt * 16 + (l & 15);
        int k  = (l >> 4) * 8 + i;
        W1A[idx] = (k < EMB) ? (_Float16)W1[j * EMB + k] : (_Float16)0.f;
    }
}

// One block = 64 batch rows, 8 waves (512 thr). Wave w: jg=w&3 owns feature cols
// [jg*64, +64) as 4 j-tiles; ig=w>>2 owns batch rows [ig*32,+32) as 2 i-tiles.
// Computes D = W2 * h^T per step: D[j][i], C-layout row=j (feature), col=i (batch)
// -> 4 consecutive j per lane -> 8B packed LDS h writes, contiguous in k for reads.
__global__ __launch_bounds__(512, 2) void rnn_kernel(
    const float* __restrict__ seq,
    const _Float16* __restrict__ W2A,
    const _Float16* __restrict__ W1A,
    const float* __restrict__ b1,
    const float* __restrict__ b2,
    const float* __restrict__ W3,
    const float* __restrict__ b3,
    float* __restrict__ out)
{
    // h double buffer: [buf][row i (64)][256 fp16 = 512B], XOR-swizzled by (i&7)<<4
    __shared__ char hbuf[2][64 * 512];

    const int tid = threadIdx.x;
    const int l   = tid & 63;
    const int wv  = tid >> 6;
    const int jg  = wv & 3;
    const int ig  = wv >> 2;
    const int lr  = l & 15;
    const int lg  = l >> 4;
    const int r0  = blockIdx.x * 64;

    // W2 A-fragments for this wave's 64 feature columns, all K: 128 VGPRs
    f16x8 w2f[4][8];
#pragma unroll
    for (int a = 0; a < 4; ++a)
#pragma unroll
        for (int kb = 0; kb < 8; ++kb)
            w2f[a][kb] = *(const f16x8*)(W2A + ((((jg * 4 + a) * 8 + kb) * 64 + l) * 8));

    f16x8 w1f[4];
#pragma unroll
    for (int a = 0; a < 4; ++a)
        w1f[a] = *(const f16x8*)(W1A + (((jg * 4 + a) * 64 + l) * 8));

    // fused bias (b1+b2) in C-layout: j = jt*16 + lg*4 + r
    f32x4 biasc[4];
#pragma unroll
    for (int a = 0; a < 4; ++a)
#pragma unroll
        for (int r = 0; r < 4; ++r) {
            int j = (jg * 4 + a) * 16 + lg * 4 + r;
            biasc[a][r] = b1[j] + b2[j];
        }

    for (int t = 0; t < T_LEN; ++t) {
        f32x4 acc[4][2];
#pragma unroll
        for (int a = 0; a < 4; ++a)
#pragma unroll
            for (int b = 0; b < 2; ++b)
                acc[a][b] = biasc[a];

        // x_proj B-fragments straight from global: B[e][i] = seq[row i][t][e]
        f16x8 sB[2];
#pragma unroll
        for (int b = 0; b < 2; ++b) {
            int row = r0 + (ig * 2 + b) * 16 + lr;
            const float* sp = seq + row * (T_LEN * EMB) + t * EMB + lg * 8;
            f32x4 f0 = *(const f32x4*)sp;                 // e = lg*8 .. +3 (<=27, valid)
            f32x4 f1 = {0.f, 0.f, 0.f, 0.f};
            if (lg < 3) f1 = *(const f32x4*)(sp + 4);     // e >= 28 zero-padded
#pragma unroll
            for (int q = 0; q < 4; ++q) {
                sB[b][q]     = (_Float16)f0[q];
                sB[b][4 + q] = (_Float16)f1[q];
            }
        }
#pragma unroll
        for (int a = 0; a < 4; ++a)
#pragma unroll
            for (int b = 0; b < 2; ++b)
                acc[a][b] = __builtin_amdgcn_mfma_f32_16x16x32_f16(w1f[a], sB[b], acc[a][b], 0, 0, 0);

        if (t > 0) {
            const char* rb = hbuf[(t + 1) & 1];   // buffer written at step t-1
#pragma unroll
            for (int kb = 0; kb < 8; ++kb) {
                f16x8 hB[2];
#pragma unroll
                for (int b = 0; b < 2; ++b) {
                    int i   = (ig * 2 + b) * 16 + lr;
                    int off = i * 512 + ((kb * 64 + lg * 16) ^ ((i & 7) << 4));
                    hB[b] = *(const f16x8*)(rb + off);
                }
#pragma unroll
                for (int a = 0; a < 4; ++a)
#pragma unroll
                    for (int b = 0; b < 2; ++b)
                        acc[a][b] = __builtin_amdgcn_mfma_f32_16x16x32_f16(w2f[a][kb], hB[b], acc[a][b], 0, 0, 0);
            }
        }

        // tanh (fp32) -> fp16 -> swizzled LDS write (8B per tile)
        char* wb = hbuf[t & 1];
#pragma unroll
        for (int a = 0; a < 4; ++a)
#pragma unroll
            for (int b = 0; b < 2; ++b) {
                f16x4 hv;
#pragma unroll
                for (int r = 0; r < 4; ++r) {
                    float y = acc[a][b][r];
                    float e = __expf(2.f * y);
                    hv[r] = (_Float16)(1.f - 2.f / (e + 1.f));
                }
                int i  = (ig * 2 + b) * 16 + lr;
                int jb = ((jg * 4 + a) * 16 + lg * 4) * 2;
                *(f16x4*)(wb + (i * 512 + (jb ^ ((i & 7) << 4)))) = hv;
            }
        __syncthreads();
    }

    // head: out = h @ W3^T + b3, fp32 VALU from final h (buf[(T_LEN-1)&1])
    const char* hb = hbuf[(T_LEN - 1) & 1];
    for (int idx = tid; idx < 64 * NOUT; idx += 512) {
        int row = idx / NOUT;
        int o   = idx - row * NOUT;
        float s = b3[o];
#pragma unroll
        for (int kc = 0; kc < 32; ++kc) {
            f16x8 hv  = *(const f16x8*)(hb + row * 512 + ((kc * 16) ^ ((row & 7) << 4)));
            f32x4 w0  = *(const f32x4*)(W3 + o * HID + kc * 8);
            f32x4 w1v = *(const f32x4*)(W3 + o * HID + kc * 8 + 4);
#pragma unroll
            for (int q = 0; q < 4; ++q)
                s += (float)hv[q] * w0[q] + (float)hv[4 + q] * w1v[q];
        }
        out[(r0 + row) * NOUT + o] = s;
    }
}

extern "C" void kernel_launch(void* const* d_in, const int* in_sizes, int n_in,
                              void* d_out, int out_size, void* d_ws, size_t ws_size,
                              hipStream_t stream) {
    const float* seq = (const float*)d_in[0];
    const float* W1  = (const float*)d_in[1];
    const float* b1  = (const float*)d_in[2];
    const float* W2  = (const float*)d_in[3];
    const float* b2  = (const float*)d_in[4];
    const float* W3  = (const float*)d_in[5];
    const float* b3  = (const float*)d_in[6];
    float* outp = (float*)d_out;

    _Float16* W2A = (_Float16*)d_ws;
    _Float16* W1A = (_Float16*)((char*)d_ws + 65536 * sizeof(_Float16));

    prep_kernel<<<256, 256, 0, stream>>>(W1, W2, W2A, W1A);
    rnn_kernel<<<BATCH / 64, 512, 0, stream>>>(seq, W2A, W1A, b1, b2, W3, b3, outp);
}

// Round 2
// 192.103 us; speedup vs baseline: 1.3519x; 1.3519x over previous
//
#include <hip/hip_runtime.h>
#include <hip/hip_bf16.h>

#define T_LEN 28
#define EMB   28
#define HID   256
#define NOUT  10
#define BATCH 32768

typedef _Float16 f16x8 __attribute__((ext_vector_type(8)));
typedef _Float16 f16x4 __attribute__((ext_vector_type(4)));
typedef float    f32x4 __attribute__((ext_vector_type(4)));

// Re-layout W1/W2 into fp16 MFMA A-operand fragments.
// W2A: [jt(16)][kb(8)][lane(64)][i(8)] -> A[j][k], j = jt*16+(l&15), k = kb*32+(l>>4)*8+i
// W1A: [jt(16)][lane(64)][i(8)]        -> A[j][e], e = (l>>4)*8+i
//      e==28 carries the fused bias (b1+b2), matched by B[28][i] = 1.0; e>28 zero.
__global__ __launch_bounds__(256) void prep_kernel(
    const float* __restrict__ W1, const float* __restrict__ W2,
    const float* __restrict__ b1, const float* __restrict__ b2,
    _Float16* __restrict__ W2A, _Float16* __restrict__ W1A) {
    int idx = blockIdx.x * 256 + threadIdx.x;
    if (idx < 65536) {
        int i  = idx & 7;
        int l  = (idx >> 3) & 63;
        int kb = (idx >> 9) & 7;
        int jt = idx >> 12;
        int j  = jt * 16 + (l & 15);
        int k  = kb * 32 + (l >> 4) * 8 + i;
        W2A[idx] = (_Float16)W2[j * HID + k];
    }
    if (idx < 8192) {
        int i  = idx & 7;
        int l  = (idx >> 3) & 63;
        int jt = idx >> 9;
        int j  = jt * 16 + (l & 15);
        int k  = (l >> 4) * 8 + i;
        float v = (k < EMB) ? W1[j * EMB + k] : (k == EMB ? (b1[j] + b2[j]) : 0.f);
        W1A[idx] = (_Float16)v;
    }
}

// Block = 16 batch rows, 512 threads = 8 waves. Wave w owns 32 feature cols
// (2 j-tiles). h lives in LDS in k-major chunk layout:
//   h16[c(0..31)][row(0..15)] of 16B chunks: chunk c holds k = c*8..c*8+7.
// Read (B-frag, row i=lr, k-window kb): addr = base + lane*16 + kb*1024  (linear!)
// x_proj B-frags for ALL t staged in LDS once at start (28 KB), bias slot e=28 -> 1.0.
__global__ __launch_bounds__(512, 4) void rnn_kernel(
    const float* __restrict__ seq,
    const _Float16* __restrict__ W2A,
    const _Float16* __restrict__ W1A,
    const float* __restrict__ W3,
    const float* __restrict__ b3,
    float* __restrict__ out)
{
    // LDS: x frags 28 KB | h double buffer 2 x 8 KB
    __shared__ __align__(16) char lds[T_LEN * 1024 + 2 * 8192];
    char* const xls = lds;
    char* const hls = lds + T_LEN * 1024;

    const int tid = threadIdx.x;
    const int l   = tid & 63;
    const int wv  = tid >> 6;         // 0..7 = jg
    const int lr  = l & 15;
    const int lg  = l >> 4;
    const int r0  = blockIdx.x * 16;

    // ---- stage seq tile -> x B-frags in LDS (coalesced: 112 threads sweep one row) ----
    for (int idx = tid; idx < 16 * T_LEN * 4; idx += 512) {
        int i  = idx / 112;           // row in tile
        int tc = idx - i * 112;
        int t  = tc >> 2;
        int c  = tc & 3;              // k-chunk (8 halves)
        const float* sp = seq + (size_t)(r0 + i) * (T_LEN * EMB) + t * EMB + c * 8;
        f32x4 f0 = *(const f32x4*)sp;
        f32x4 f1;
        if (c < 3) f1 = *(const f32x4*)(sp + 4);
        else       f1 = (f32x4){1.f, 0.f, 0.f, 0.f};   // e=28 bias slot
        f16x8 v;
#pragma unroll
        for (int q = 0; q < 4; ++q) { v[q] = (_Float16)f0[q]; v[4 + q] = (_Float16)f1[q]; }
        *(f16x8*)(xls + ((t * 4 + c) * 16 + i) * 16) = v;
    }

    // ---- W1/W2 fragments for this wave's 32 cols (jt = wv*2 + a) ----
    f16x8 w2f[2][8];
#pragma unroll
    for (int a = 0; a < 2; ++a)
#pragma unroll
        for (int kb = 0; kb < 8; ++kb)
            w2f[a][kb] = *(const f16x8*)(W2A + ((((wv * 2 + a) * 8 + kb) * 64 + l) * 8));
    f16x8 w1f[2];
#pragma unroll
    for (int a = 0; a < 2; ++a)
        w1f[a] = *(const f16x8*)(W1A + (((wv * 2 + a) * 64 + l) * 8));

    __syncthreads();   // x frags ready

    for (int t = 0; t < T_LEN; ++t) {
        f32x4 acc[2];
#pragma unroll
        for (int a = 0; a < 2; ++a) acc[a] = (f32x4){0.f, 0.f, 0.f, 0.f};

        // x_proj contribution (k=32 incl. bias column)
        f16x8 xB = *(const f16x8*)(xls + t * 1024 + l * 16);
#pragma unroll
        for (int a = 0; a < 2; ++a)
            acc[a] = __builtin_amdgcn_mfma_f32_16x16x32_f16(w1f[a], xB, acc[a], 0, 0, 0);

        if (t > 0) {
            const char* rp = hls + ((t + 1) & 1) * 8192 + l * 16;   // linear 16B/lane
#pragma unroll
            for (int kb = 0; kb < 8; ++kb) {
                f16x8 hB = *(const f16x8*)(rp + kb * 1024);
#pragma unroll
                for (int a = 0; a < 2; ++a)
                    acc[a] = __builtin_amdgcn_mfma_f32_16x16x32_f16(w2f[a][kb], hB, acc[a], 0, 0, 0);
            }
        }

        // tanh -> fp16 -> k-major LDS write (8B, bank-clean)
        char* wb = hls + (t & 1) * 8192;
#pragma unroll
        for (int a = 0; a < 2; ++a) {
            f16x4 hv;
#pragma unroll
            for (int r = 0; r < 4; ++r) {
                float y = acc[a][r];
                float e = __expf(2.f * y);
                hv[r] = (_Float16)(1.f - 2.f / (e + 1.f));
            }
            int c = (wv * 2 + a) * 2 + (lg >> 1);      // j-chunk
            *(f16x4*)(wb + (c * 16 + lr) * 16 + (lg & 1) * 8) = hv;
        }
        __syncthreads();
    }

    // ---- head: out = h @ W3^T + b3 (final h in buffer (T_LEN-1)&1 = 1) ----
    const char* hb = hls + ((T_LEN - 1) & 1) * 8192;
    for (int idx = tid; idx < 16 * NOUT; idx += 512) {
        int i = idx / NOUT;
        int o = idx - i * NOUT;
        float s = b3[o];
#pragma unroll
        for (int c = 0; c < 32; ++c) {
            f16x8 hv  = *(const f16x8*)(hb + (c * 16 + i) * 16);
            f32x4 w0  = *(const f32x4*)(W3 + o * HID + c * 8);
            f32x4 w1v = *(const f32x4*)(W3 + o * HID + c * 8 + 4);
#pragma unroll
            for (int q = 0; q < 4; ++q)
                s += (float)hv[q] * w0[q] + (float)hv[4 + q] * w1v[q];
        }
        out[(size_t)(r0 + i) * NOUT + o] = s;
    }
}

extern "C" void kernel_launch(void* const* d_in, const int* in_sizes, int n_in,
                              void* d_out, int out_size, void* d_ws, size_t ws_size,
                              hipStream_t stream) {
    const float* seq = (const float*)d_in[0];
    const float* W1  = (const float*)d_in[1];
    const float* b1  = (const float*)d_in[2];
    const float* W2  = (const float*)d_in[3];
    const float* b2  = (const float*)d_in[4];
    const float* W3  = (const float*)d_in[5];
    const float* b3  = (const float*)d_in[6];
    float* outp = (float*)d_out;

    _Float16* W2A = (_Float16*)d_ws;
    _Float16* W1A = (_Float16*)((char*)d_ws + 65536 * sizeof(_Float16));

    prep_kernel<<<256, 256, 0, stream>>>(W1, W2, b1, b2, W2A, W1A);
    rnn_kernel<<<BATCH / 16, 512, 0, stream>>>(seq, W2A, W1A, W3, b3, outp);
}

// Round 3
// 150.976 us; speedup vs baseline: 1.7201x; 1.2724x over previous
//
#include <hip/hip_runtime.h>
#include <hip/hip_bf16.h>

#define T_LEN 28
#define EMB   28
#define HID   256
#define NOUT  10
#define BATCH 32768

typedef _Float16 f16x8 __attribute__((ext_vector_type(8)));
typedef _Float16 f16x4 __attribute__((ext_vector_type(4)));
typedef float    f32x4 __attribute__((ext_vector_type(4)));

// Re-layout W1/W2 into fp16 MFMA A-operand fragments.
// W2A: [jt(16)][kb(8)][lane(64)][i(8)] -> A[j][k], j = jt*16+(l&15), k = kb*32+(l>>4)*8+i
// W1A: [jt(16)][lane(64)][i(8)]        -> A[j][e], e = (l>>4)*8+i
//      e==28 carries the fused bias (b1+b2), matched by B[28][i] = 1.0; e>28 zero.
__global__ __launch_bounds__(256) void prep_kernel(
    const float* __restrict__ W1, const float* __restrict__ W2,
    const float* __restrict__ b1, const float* __restrict__ b2,
    _Float16* __restrict__ W2A, _Float16* __restrict__ W1A) {
    int idx = blockIdx.x * 256 + threadIdx.x;
    if (idx < 65536) {
        int i  = idx & 7;
        int l  = (idx >> 3) & 63;
        int kb = (idx >> 9) & 7;
        int jt = idx >> 12;
        int j  = jt * 16 + (l & 15);
        int k  = kb * 32 + (l >> 4) * 8 + i;
        W2A[idx] = (_Float16)W2[j * HID + k];
    }
    if (idx < 8192) {
        int i  = idx & 7;
        int l  = (idx >> 3) & 63;
        int jt = idx >> 9;
        int j  = jt * 16 + (l & 15);
        int k  = (l >> 4) * 8 + i;
        float v = (k < EMB) ? W1[j * EMB + k] : (k == EMB ? (b1[j] + b2[j]) : 0.f);
        W1A[idx] = (_Float16)v;
    }
}

// Block = 16 batch rows, 256 threads = 4 waves. Wave wv owns 64 feature cols
// (4 j-tiles: jt = wv*4+a) -> w2f = 128 VGPRs, B-read multiplicity 4 (was 8).
// h in LDS, k-major chunks: h16[c(0..31)][row(0..15)] 16B chunks (chunk c = k c*8..c*8+7).
// B-frag read (row i=lr, k-window kb): addr = base + lane*16 + kb*1024 (linear, conflict-free).
__global__ __launch_bounds__(256, 2) void rnn_kernel(
    const float* __restrict__ seq,
    const _Float16* __restrict__ W2A,
    const _Float16* __restrict__ W1A,
    const float* __restrict__ W3,
    const float* __restrict__ b3,
    float* __restrict__ out)
{
    // LDS: x frags 28 KB | h double buffer 2 x 8 KB
    __shared__ __align__(16) char lds[T_LEN * 1024 + 2 * 8192];
    char* const xls = lds;
    char* const hls = lds + T_LEN * 1024;

    const int tid = threadIdx.x;
    const int l   = tid & 63;
    const int wv  = tid >> 6;         // 0..3
    const int lr  = l & 15;
    const int lg  = l >> 4;
    const int r0  = blockIdx.x * 16;

    // ---- stage seq tile -> x B-frags in LDS (7 iters/thread, once) ----
    for (int idx = tid; idx < 16 * T_LEN * 4; idx += 256) {
        int i  = idx / 112;           // row in tile
        int tc = idx - i * 112;
        int t  = tc >> 2;
        int c  = tc & 3;              // k-chunk (8 halves)
        const float* sp = seq + (size_t)(r0 + i) * (T_LEN * EMB) + t * EMB + c * 8;
        f32x4 f0 = *(const f32x4*)sp;
        f32x4 f1;
        if (c < 3) f1 = *(const f32x4*)(sp + 4);
        else       f1 = (f32x4){1.f, 0.f, 0.f, 0.f};   // e=28 bias slot
        f16x8 v;
#pragma unroll
        for (int q = 0; q < 4; ++q) { v[q] = (_Float16)f0[q]; v[4 + q] = (_Float16)f1[q]; }
        *(f16x8*)(xls + ((t * 4 + c) * 16 + i) * 16) = v;
    }

    // ---- W1/W2 fragments: 4 j-tiles (jt = wv*4 + a) ----
    f16x8 w2f[4][8];
#pragma unroll
    for (int a = 0; a < 4; ++a)
#pragma unroll
        for (int kb = 0; kb < 8; ++kb)
            w2f[a][kb] = *(const f16x8*)(W2A + ((((wv * 4 + a) * 8 + kb) * 64 + l) * 8));
    f16x8 w1f[4];
#pragma unroll
    for (int a = 0; a < 4; ++a)
        w1f[a] = *(const f16x8*)(W1A + (((wv * 4 + a) * 64 + l) * 8));

    __syncthreads();   // x frags ready

    for (int t = 0; t < T_LEN; ++t) {
        f32x4 acc[4];
#pragma unroll
        for (int a = 0; a < 4; ++a) acc[a] = (f32x4){0.f, 0.f, 0.f, 0.f};

        // x_proj contribution (k=32 incl. bias column)
        f16x8 xB = *(const f16x8*)(xls + t * 1024 + l * 16);
#pragma unroll
        for (int a = 0; a < 4; ++a)
            acc[a] = __builtin_amdgcn_mfma_f32_16x16x32_f16(w1f[a], xB, acc[a], 0, 0, 0);

        if (t > 0) {
            const char* rp = hls + ((t + 1) & 1) * 8192 + l * 16;   // linear 16B/lane
            f16x8 hB = *(const f16x8*)rp;
#pragma unroll
            for (int kb = 0; kb < 8; ++kb) {
                f16x8 hN;
                if (kb < 7) hN = *(const f16x8*)(rp + (kb + 1) * 1024);
#pragma unroll
                for (int a = 0; a < 4; ++a)
                    acc[a] = __builtin_amdgcn_mfma_f32_16x16x32_f16(w2f[a][kb], hB, acc[a], 0, 0, 0);
                hB = hN;
            }
        }

        // tanh (exp2 + rcp, no IEEE div) -> fp16 -> k-major LDS write (8B, bank-clean)
        char* wb = hls + (t & 1) * 8192;
#pragma unroll
        for (int a = 0; a < 4; ++a) {
            f16x4 hv;
#pragma unroll
            for (int r = 0; r < 4; ++r) {
                float y = acc[a][r];
                float e = __builtin_amdgcn_exp2f(2.8853900817779268f * y); // e^(2y)
                float rc = __builtin_amdgcn_rcpf(e + 1.f);
                hv[r] = (_Float16)__builtin_fmaf(-2.f, rc, 1.f);
            }
            int c = (wv * 4 + a) * 2 + (lg >> 1);      // j-chunk
            *(f16x4*)(wb + (c * 16 + lr) * 16 + (lg & 1) * 8) = hv;
        }
        __syncthreads();
    }

    // ---- head: out = h @ W3^T + b3 (final h in buffer (T_LEN-1)&1 = 1) ----
    const char* hb = hls + ((T_LEN - 1) & 1) * 8192;
    for (int idx = tid; idx < 16 * NOUT; idx += 256) {
        int i = idx / NOUT;
        int o = idx - i * NOUT;
        float s = b3[o];
#pragma unroll
        for (int c = 0; c < 32; ++c) {
            f16x8 hv  = *(const f16x8*)(hb + (c * 16 + i) * 16);
            f32x4 w0  = *(const f32x4*)(W3 + o * HID + c * 8);
            f32x4 w1v = *(const f32x4*)(W3 + o * HID + c * 8 + 4);
#pragma unroll
            for (int q = 0; q < 4; ++q)
                s += (float)hv[q] * w0[q] + (float)hv[4 + q] * w1v[q];
        }
        out[(size_t)(r0 + i) * NOUT + o] = s;
    }
}

extern "C" void kernel_launch(void* const* d_in, const int* in_sizes, int n_in,
                              void* d_out, int out_size, void* d_ws, size_t ws_size,
                              hipStream_t stream) {
    const float* seq = (const float*)d_in[0];
    const float* W1  = (const float*)d_in[1];
    const float* b1  = (const float*)d_in[2];
    const float* W2  = (const float*)d_in[3];
    const float* b2  = (const float*)d_in[4];
    const float* W3  = (const float*)d_in[5];
    const float* b3  = (const float*)d_in[6];
    float* outp = (float*)d_out;

    _Float16* W2A = (_Float16*)d_ws;
    _Float16* W1A = (_Float16*)((char*)d_ws + 65536 * sizeof(_Float16));

    prep_kernel<<<256, 256, 0, stream>>>(W1, W2, b1, b2, W2A, W1A);
    rnn_kernel<<<BATCH / 16, 256, 0, stream>>>(seq, W2A, W1A, W3, b3, outp);
}